// Round 2
// baseline (341.024 us; speedup 1.0000x reference)
//
#include <hip/hip_runtime.h>
#include <math.h>

#define B_   8
#define C_   128
#define L_   8192
#define O_   128
#define OH   64           // outputs per block (o-split)
#define POS_ 10
#define CHIN 798          // (2*C + POS) * 3
#define TL   128
#define NT   256

// ---------------------------------------------------------------------------
// Mask dtype detection (bool-byte vs int32 vs int64), see R0 notes.
// flag: 1 = byte/bool, 0 = int32, 2 = int64
// ---------------------------------------------------------------------------
__global__ void detect_mask_kernel(const unsigned char* __restrict__ m, int* __restrict__ flag) {
    __shared__ int s_sub, s_mid;
    if (threadIdx.x == 0) { s_sub = 0; s_mid = 0; }
    __syncthreads();
    int a = 0, b = 0;
    const int n = B_ * L_;
    for (int i = threadIdx.x; i < n; i += blockDim.x) {
        unsigned char v = m[i];
        if (v) {
            if (i & 3) a = 1;
            else if ((i & 7) == 4) b = 1;
        }
    }
    if (a) atomicOr(&s_sub, 1);
    if (b) atomicOr(&s_mid, 1);
    __syncthreads();
    if (threadIdx.x == 0) {
        *flag = s_sub ? 1 : (s_mid ? 0 : 2);
    }
}

// ---------------------------------------------------------------------------
// Main kernel: one block = (b, 128-wide l tile, 64-output half).
// 256 threads: tid = ot*16 + lt ; each thread owns 4 outputs x 8 positions.
// K-loop: 17 chunks of 16 channels (8 direct, 8 gathered, 1 penc(10)).
// y[b,o,l] = sum_{c,k} W[o,3c+k] * feat[b,c,l+k-1]  (zero-padded) + bias, *mask
// ---------------------------------------------------------------------------
__global__ __launch_bounds__(NT, 4)
void cc_main_kernel(const float* __restrict__ inputs,
                    const int* __restrict__ conn,
                    const unsigned char* __restrict__ mask,
                    const float* __restrict__ W,
                    const float* __restrict__ bias,
                    float* __restrict__ out,
                    const int* __restrict__ mflag_p) {
    __shared__ int   conn_s[TL + 2];
    __shared__ float feat_s[16][132];   // 16B-aligned rows (132*4 = 528)
    __shared__ float Ws[48][68];        // kk-major; stride 68: (4kk+o)%32 -> 2-way writes, aligned reads

    const int b   = blockIdx.y;
    const int l0  = blockIdx.x * TL;
    const int ob  = blockIdx.z * OH;    // output-half base
    const int tid = threadIdx.x;
    const int ot  = tid >> 4;          // 0..15
    const int lt  = tid & 15;          // 0..15
    const int o0  = ot * 4;            // local output base (0..60)
    const int ll  = lt * 8;

    // conn for this tile incl. halo; -1 marks out-of-range l (zero padding)
    for (int j = tid; j < TL + 2; j += NT) {
        int lg = l0 - 1 + j;
        conn_s[j] = ((unsigned)lg < (unsigned)L_) ? conn[b * L_ + lg] : -1;
    }

    float acc[4][8];
    #pragma unroll
    for (int i = 0; i < 4; ++i)
        #pragma unroll
        for (int j = 0; j < 8; ++j) acc[i][j] = 0.f;

    const int tc = ot;   // feat staging row
    const int tj = lt;   // feat staging col phase

    for (int chunk = 0; chunk < 17; ++chunk) {
        const int CN   = (chunk < 16) ? 16 : POS_;
        const int CN3  = 3 * CN;
        const int cg0  = chunk * 16;
        const int col0 = 3 * cg0;

        __syncthreads();   // previous chunk's compute done (also covers conn_s)

        // ---- stage W slice: Ws[kk][o] = W[ob+o][col0+kk], kk in [0,CN3), o in [0,64)
        // lanes: (16 o) x (16 contiguous kk) -> 64B coalesced runs; LDS writes 2-way.
        {
            const int os = tid >> 4;     // o sub-offset 0..15
            const int ks = tid & 15;     // kk sub-offset 0..15
            for (int kb = 0; kb < CN3; kb += 16) {
                int kk = kb + ks;
                bool ok = (kk < CN3);
                #pragma unroll
                for (int obk = 0; obk < OH; obk += 16) {
                    int o = obk + os;
                    if (ok) Ws[kk][o] = W[(size_t)(ob + o) * CHIN + col0 + kk];
                }
            }
        }

        // ---- stage feature rows [CN][TL+2]
        if (chunk < 8) {
            const float* src = inputs + ((size_t)b * C_ + (cg0 + tc)) * L_;
            for (int j = tj; j < TL + 2; j += 16) {
                int lg = l0 - 1 + j;
                feat_s[tc][j] = ((unsigned)lg < (unsigned)L_) ? src[lg] : 0.f;
            }
        } else if (chunk < 16) {
            const float* src = inputs + ((size_t)b * C_ + (cg0 - 128 + tc)) * L_;
            for (int j = tj; j < TL + 2; j += 16) {
                int cj = conn_s[j];
                feat_s[tc][j] = (cj >= 0) ? src[cj] : 0.f;
            }
        } else {
            if (tc < POS_) {
                const float sc = (float)(1 << tc);   // 2^p, exact
                for (int j = tj; j < TL + 2; j += 16) {
                    int cj = conn_s[j];
                    int lg = l0 - 1 + j;
                    float v = 0.f;
                    if (cj >= 0) {
                        float d = (float)(lg - cj);
                        v = sinf((sc * d) / 1000.0f);   // match reference op order
                    }
                    feat_s[tc][j] = v;
                }
            }
        }

        __syncthreads();

        // ---- compute: per channel, 10-wide sliding window, 3 taps, 4x8 outer product
        for (int c = 0; c < CN; ++c) {
            float f[10];
            {
                float4 fa = *(const float4*)&feat_s[c][ll];
                float4 fb = *(const float4*)&feat_s[c][ll + 4];
                float2 fc2 = *(const float2*)&feat_s[c][ll + 8];
                f[0]=fa.x; f[1]=fa.y; f[2]=fa.z; f[3]=fa.w;
                f[4]=fb.x; f[5]=fb.y; f[6]=fb.z; f[7]=fb.w;
                f[8]=fc2.x; f[9]=fc2.y;
            }
            #pragma unroll
            for (int k = 0; k < 3; ++k) {
                float4 wv = *(const float4*)&Ws[c * 3 + k][o0];
                float w[4];
                w[0]=wv.x; w[1]=wv.y; w[2]=wv.z; w[3]=wv.w;
                #pragma unroll
                for (int oi = 0; oi < 4; ++oi)
                    #pragma unroll
                    for (int li = 0; li < 8; ++li)
                        acc[oi][li] = fmaf(w[oi], f[li + k], acc[oi][li]);
            }
        }
    }

    // ---- epilogue: bias, mask, store
    const int mflag = *mflag_p;
    const int lbase = l0 + ll;
    float mv[8];
    if (mflag == 1) {
        #pragma unroll
        for (int li = 0; li < 8; ++li)
            mv[li] = mask[b * L_ + lbase + li] ? 1.f : 0.f;
    } else if (mflag == 0) {
        const int* mi = (const int*)mask;
        #pragma unroll
        for (int li = 0; li < 8; ++li)
            mv[li] = mi[b * L_ + lbase + li] ? 1.f : 0.f;
    } else {
        const int* mi = (const int*)mask;   // int64: test low word
        #pragma unroll
        for (int li = 0; li < 8; ++li)
            mv[li] = mi[2 * (b * L_ + lbase + li)] ? 1.f : 0.f;
    }

    #pragma unroll
    for (int oi = 0; oi < 4; ++oi) {
        float bo = bias[ob + o0 + oi];
        float4 r0, r1;
        r0.x = (acc[oi][0] + bo) * mv[0];
        r0.y = (acc[oi][1] + bo) * mv[1];
        r0.z = (acc[oi][2] + bo) * mv[2];
        r0.w = (acc[oi][3] + bo) * mv[3];
        r1.x = (acc[oi][4] + bo) * mv[4];
        r1.y = (acc[oi][5] + bo) * mv[5];
        r1.z = (acc[oi][6] + bo) * mv[6];
        r1.w = (acc[oi][7] + bo) * mv[7];
        float* dst = out + ((size_t)b * O_ + ob + o0 + oi) * L_ + lbase;
        *(float4*)&dst[0] = r0;
        *(float4*)&dst[4] = r1;
    }
}

extern "C" void kernel_launch(void* const* d_in, const int* in_sizes, int n_in,
                              void* d_out, int out_size, void* d_ws, size_t ws_size,
                              hipStream_t stream) {
    const float*         inputs = (const float*)d_in[0];
    const int*           conn   = (const int*)d_in[1];
    const unsigned char* mask   = (const unsigned char*)d_in[2];
    const float*         W      = (const float*)d_in[3];
    const float*         bias   = (const float*)d_in[4];
    float*               out    = (float*)d_out;
    int*                 mflag  = (int*)d_ws;

    detect_mask_kernel<<<1, 256, 0, stream>>>(mask, mflag);

    dim3 grid(L_ / TL, B_, 2);
    cc_main_kernel<<<grid, NT, 0, stream>>>(inputs, conn, mask, W, bias, out, mflag);
}

// Round 5
// 176.149 us; speedup vs baseline: 1.9360x; 1.9360x over previous
//
#include <hip/hip_runtime.h>
#include <math.h>

#define B_    8
#define C_    128
#define L_    8192
#define O_    128
#define POS_  10
#define CHIN  798
#define CH_   266          // 128 direct + 128 gathered + 10 penc
#define CPAD  288          // 9 chunks * 32
#define NCH   9            // K chunks of 32 channels
#define TL2   256          // l-tile for GEMM
#define G_ELEMS  ((size_t)B_ * L_ * CPAD)         // 18,874,368 f32
#define WT_ELEMS ((size_t)3 * O_ * CPAD)          // 110,592 f32

typedef short short8 __attribute__((ext_vector_type(8)));
typedef float f32x4  __attribute__((ext_vector_type(4)));

__device__ __forceinline__ unsigned bf16_rne(float f) {
    unsigned u = __float_as_uint(f);
    return (u + 0x7FFFu + ((u >> 16) & 1u)) >> 16;
}

// ---------------------------------------------------------------------------
// mask dtype detection (bool-byte vs int32 vs int64): flag 1=byte,0=i32,2=i64
// ---------------------------------------------------------------------------
__global__ void detect_mask_kernel(const unsigned char* __restrict__ m, int* __restrict__ flag) {
    __shared__ int s_sub, s_mid;
    if (threadIdx.x == 0) { s_sub = 0; s_mid = 0; }
    __syncthreads();
    int a = 0, b = 0;
    const int n = B_ * L_;
    for (int i = threadIdx.x; i < n; i += blockDim.x) {
        unsigned char v = m[i];
        if (v) { if (i & 3) a = 1; else if ((i & 7) == 4) b = 1; }
    }
    if (a) atomicOr(&s_sub, 1);
    if (b) atomicOr(&s_mid, 1);
    __syncthreads();
    if (threadIdx.x == 0) *flag = s_sub ? 1 : (s_mid ? 0 : 2);
}

// ---------------------------------------------------------------------------
// K0: transpose inputs[b,c,l] -> G[b,l,c] (direct channels 0..127), f32
// ---------------------------------------------------------------------------
__global__ __launch_bounds__(256, 4)
void k0_transpose(const float* __restrict__ inputs, float* __restrict__ G) {
    __shared__ float tile[64][65];
    const int bid = blockIdx.x;
    const int b  = bid & 7;          // b -> XCD affinity
    const int r  = bid >> 3;
    const int c0 = (r & 1) * 64;
    const int l0 = (r >> 1) * 64;
    const int ty = threadIdx.x >> 6, tx = threadIdx.x & 63;

    #pragma unroll
    for (int it = 0; it < 16; ++it) {
        int cl = it * 4 + ty;
        tile[cl][tx] = inputs[((size_t)(b * C_ + c0 + cl)) * L_ + l0 + tx];
    }
    __syncthreads();
    #pragma unroll
    for (int it = 0; it < 16; ++it) {
        int ll = it * 4 + ty;
        G[((size_t)(b * L_ + l0 + ll)) * CPAD + c0 + tx] = tile[tx][ll];
    }
}

// ---------------------------------------------------------------------------
// K1: gather rows + positional encoding into G
//   G[b,l,128+c] = G[b,conn[b,l],c]  (c<128)
//   G[b,l,256+p] = sin(2^p * (l-conn)/1000) for p<10, else 0 (p<32)
// ---------------------------------------------------------------------------
__global__ __launch_bounds__(256, 4)
void k1_gather_penc(const int* __restrict__ conn, float* __restrict__ G) {
    const int bid = blockIdx.x;
    const int b  = bid & 7;                  // same-b blocks share an XCD's L2
    const int l0 = (bid >> 3) * 64;
    const int tid = threadIdx.x;
    const int wv = tid >> 6, lane = tid & 63;

    for (int i = 0; i < 16; ++i) {
        int l  = l0 + wv * 16 + i;
        int cj = conn[b * L_ + l];
        float2 s = *(const float2*)&G[((size_t)(b * L_ + cj)) * CPAD + lane * 2];
        *(float2*)&G[((size_t)(b * L_ + l)) * CPAD + 128 + lane * 2] = s;
    }

    // penc: 64 l x 32 c' per block; thread -> (l, 8-wide c' group)
    {
        int l   = l0 + (tid >> 2);
        int sub = tid & 3;
        int cj  = conn[b * L_ + l];
        float d = (float)(l - cj);
        float v[8];
        #pragma unroll
        for (int e = 0; e < 8; ++e) {
            int p = sub * 8 + e;
            if (p < POS_) {
                float sc = (float)(1 << p);
                v[e] = sinf((sc * d) / 1000.0f);
            } else v[e] = 0.f;
        }
        float* dst = &G[((size_t)(b * L_ + l)) * CPAD + 256 + sub * 8];
        *(float4*)&dst[0] = make_float4(v[0], v[1], v[2], v[3]);
        *(float4*)&dst[4] = make_float4(v[4], v[5], v[6], v[7]);
    }
}

// ---------------------------------------------------------------------------
// K1b: Wt[tap][o][c] = W[o][3c+tap] (c<266 else 0)
// ---------------------------------------------------------------------------
__global__ void k1b_wt(const float* __restrict__ W, float* __restrict__ Wt) {
    int idx = blockIdx.x * 256 + threadIdx.x;
    if (idx >= (int)WT_ELEMS) return;
    int c   = idx % CPAD;
    int rem = idx / CPAD;
    int o   = rem & 127;
    int t   = rem >> 7;
    Wt[idx] = (c < CH_) ? W[o * CHIN + 3 * c + t] : 0.f;
}

// ---------------------------------------------------------------------------
// K2: MFMA GEMM. block = (b, 256-l tile), 512 threads = 8 waves (2o x 4l).
// wave tile 64o x 64l = 16 frags of 16x16; K = 9 chunks x 32 ch x 3 taps,
// bf16x3 split (AhBh + AlBh + AhBl).
// ---------------------------------------------------------------------------
__global__ __launch_bounds__(512, 2)
void k2_gemm(const float* __restrict__ G, const float* __restrict__ Wt,
             const unsigned char* __restrict__ mask,
             const float* __restrict__ bias,
             float* __restrict__ out,
             const int* __restrict__ mflag_p) {
    __shared__ short Bs_h[260][40];    // rows l0-1 .. l0+256 ; stride 40 bf16 = 80B
    __shared__ short Bs_l[260][40];
    __shared__ short As_h[3][128][40]; // [tap][o][c]
    __shared__ short As_l[3][128][40];

    const int lt0 = blockIdx.x;        // 0..31
    const int b   = blockIdx.y;
    const int l0  = lt0 * TL2;
    const int tid  = threadIdx.x;
    const int wave = tid >> 6;
    const int lane = tid & 63;
    const int wo = wave & 1;           // o-half
    const int wl = wave >> 1;          // l-quarter
    const int g  = lane >> 4;          // k-group 0..3
    const int ln = lane & 15;

    f32x4 acc[4][4];
    #pragma unroll
    for (int m = 0; m < 4; ++m)
        #pragma unroll
        for (int n = 0; n < 4; ++n) acc[m][n] = (f32x4)0.f;

    for (int ch = 0; ch < NCH; ++ch) {
        const int c0 = ch * 32;
        __syncthreads();

        // stage A: Wt[t][o][c0..c0+31] -> bf16 hi/lo ; 3072 float4-quads
        for (int q = tid; q < 3072; q += 512) {
            int c4 = (q & 7) * 4;
            int o  = (q >> 3) & 127;
            int t  = q >> 10;
            float4 w4 = *(const float4*)&Wt[((size_t)(t * O_ + o)) * CPAD + c0 + c4];
            unsigned h0 = bf16_rne(w4.x), h1 = bf16_rne(w4.y), h2 = bf16_rne(w4.z), h3 = bf16_rne(w4.w);
            float l0f = w4.x - __uint_as_float(h0 << 16);
            float l1f = w4.y - __uint_as_float(h1 << 16);
            float l2f = w4.z - __uint_as_float(h2 << 16);
            float l3f = w4.w - __uint_as_float(h3 << 16);
            uint2 hw, lw;
            hw.x = h0 | (h1 << 16); hw.y = h2 | (h3 << 16);
            lw.x = bf16_rne(l0f) | (bf16_rne(l1f) << 16);
            lw.y = bf16_rne(l2f) | (bf16_rne(l3f) << 16);
            *(uint2*)&As_h[t][o][c4] = hw;
            *(uint2*)&As_l[t][o][c4] = lw;
        }

        // stage B: G[b][l0-1+j][c0..c0+31] -> bf16 hi/lo ; 258 rows x 8 quads
        for (int q = tid; q < 2064; q += 512) {
            int c4 = (q & 7) * 4;
            int j  = q >> 3;
            int l  = l0 - 1 + j;
            float4 g4 = make_float4(0.f, 0.f, 0.f, 0.f);
            if ((unsigned)l < (unsigned)L_)
                g4 = *(const float4*)&G[((size_t)(b * L_ + l)) * CPAD + c0 + c4];
            unsigned h0 = bf16_rne(g4.x), h1 = bf16_rne(g4.y), h2 = bf16_rne(g4.z), h3 = bf16_rne(g4.w);
            float l0f = g4.x - __uint_as_float(h0 << 16);
            float l1f = g4.y - __uint_as_float(h1 << 16);
            float l2f = g4.z - __uint_as_float(h2 << 16);
            float l3f = g4.w - __uint_as_float(h3 << 16);
            uint2 hw, lw;
            hw.x = h0 | (h1 << 16); hw.y = h2 | (h3 << 16);
            lw.x = bf16_rne(l0f) | (bf16_rne(l1f) << 16);
            lw.y = bf16_rne(l2f) | (bf16_rne(l3f) << 16);
            *(uint2*)&Bs_h[j][c4] = hw;
            *(uint2*)&Bs_l[j][c4] = lw;
        }

        __syncthreads();

        // compute: 3 taps x (4m x 4n) x 3 split terms
        #pragma unroll
        for (int t = 0; t < 3; ++t) {
            short8 bh[4], bl[4];
            #pragma unroll
            for (int n = 0; n < 4; ++n) {
                int row = wl * 64 + n * 16 + ln + t;   // = (l - l0) + (t-1) + 1
                bh[n] = *(const short8*)&Bs_h[row][8 * g];
                bl[n] = *(const short8*)&Bs_l[row][8 * g];
            }
            #pragma unroll
            for (int m = 0; m < 4; ++m) {
                int orow = wo * 64 + m * 16 + ln;
                short8 ah = *(const short8*)&As_h[t][orow][8 * g];
                short8 al = *(const short8*)&As_l[t][orow][8 * g];
                #pragma unroll
                for (int n = 0; n < 4; ++n) {
                    acc[m][n] = __builtin_amdgcn_mfma_f32_16x16x32_bf16(ah, bh[n], acc[m][n], 0, 0, 0);
                    acc[m][n] = __builtin_amdgcn_mfma_f32_16x16x32_bf16(al, bh[n], acc[m][n], 0, 0, 0);
                    acc[m][n] = __builtin_amdgcn_mfma_f32_16x16x32_bf16(ah, bl[n], acc[m][n], 0, 0, 0);
                }
            }
        }
    }

    // epilogue: bias + mask + store. D: col = lane&15 (l), row = (lane>>4)*4+r (o)
    const int mflag = *mflag_p;
    float mv[4];
    #pragma unroll
    for (int n = 0; n < 4; ++n) {
        int l = l0 + wl * 64 + n * 16 + ln;
        int idx = b * L_ + l;
        if (mflag == 1)      mv[n] = mask[idx] ? 1.f : 0.f;
        else if (mflag == 0) mv[n] = ((const int*)mask)[idx] ? 1.f : 0.f;
        else                 mv[n] = ((const int*)mask)[2 * idx] ? 1.f : 0.f;
    }
    #pragma unroll
    for (int m = 0; m < 4; ++m) {
        #pragma unroll
        for (int r = 0; r < 4; ++r) {
            int o = wo * 64 + m * 16 + g * 4 + r;
            float bo = bias[o];
            #pragma unroll
            for (int n = 0; n < 4; ++n) {
                int l = l0 + wl * 64 + n * 16 + ln;
                out[((size_t)(b * O_ + o)) * L_ + l] = (acc[m][n][r] + bo) * mv[n];
            }
        }
    }
}

// ---------------------------------------------------------------------------
// Fallback (R1 fp32 kernel) if workspace is too small for the MFMA path
// ---------------------------------------------------------------------------
__global__ __launch_bounds__(256, 2)
void cc_fallback_kernel(const float* __restrict__ inputs,
                        const int* __restrict__ conn,
                        const unsigned char* __restrict__ mask,
                        const float* __restrict__ W,
                        const float* __restrict__ bias,
                        float* __restrict__ out,
                        const int* __restrict__ mflag_p) {
    __shared__ int   conn_s[130];
    __shared__ float feat_s[16][132];
    __shared__ float Ws[48][136];

    const int b   = blockIdx.y;
    const int l0  = blockIdx.x * 128;
    const int tid = threadIdx.x;
    const int ot  = tid >> 4;
    const int lt  = tid & 15;
    const int o0  = ot * 8;
    const int ll  = lt * 8;

    for (int j = tid; j < 130; j += 256) {
        int lg = l0 - 1 + j;
        conn_s[j] = ((unsigned)lg < (unsigned)L_) ? conn[b * L_ + lg] : -1;
    }
    float acc[8][8];
    #pragma unroll
    for (int i = 0; i < 8; ++i)
        #pragma unroll
        for (int j = 0; j < 8; ++j) acc[i][j] = 0.f;

    const int tc = ot, tj = lt;
    for (int chunk = 0; chunk < 17; ++chunk) {
        const int CN  = (chunk < 16) ? 16 : POS_;
        const int cg0 = chunk * 16;
        const int col0 = 3 * cg0;
        __syncthreads();
        {
            const int nw = O_ * CN * 3;
            for (int idx = tid; idx < nw; idx += 256) {
                int o = idx & 127, kk = idx >> 7;
                Ws[kk][o] = W[o * CHIN + col0 + kk];
            }
        }
        if (chunk < 8) {
            const float* src = inputs + ((size_t)b * C_ + (cg0 + tc)) * L_;
            for (int j = tj; j < 130; j += 16) {
                int lg = l0 - 1 + j;
                feat_s[tc][j] = ((unsigned)lg < (unsigned)L_) ? src[lg] : 0.f;
            }
        } else if (chunk < 16) {
            const float* src = inputs + ((size_t)b * C_ + (cg0 - 128 + tc)) * L_;
            for (int j = tj; j < 130; j += 16) {
                int cj = conn_s[j];
                feat_s[tc][j] = (cj >= 0) ? src[cj] : 0.f;
            }
        } else if (tc < POS_) {
            const float sc = (float)(1 << tc);
            for (int j = tj; j < 130; j += 16) {
                int cj = conn_s[j];
                int lg = l0 - 1 + j;
                float v = 0.f;
                if (cj >= 0) v = sinf((sc * (float)(lg - cj)) / 1000.0f);
                feat_s[tc][j] = v;
            }
        }
        __syncthreads();
        for (int c = 0; c < CN; ++c) {
            float f[10];
            float4 fa = *(const float4*)&feat_s[c][ll];
            float4 fb = *(const float4*)&feat_s[c][ll + 4];
            float2 fc2 = *(const float2*)&feat_s[c][ll + 8];
            f[0]=fa.x; f[1]=fa.y; f[2]=fa.z; f[3]=fa.w;
            f[4]=fb.x; f[5]=fb.y; f[6]=fb.z; f[7]=fb.w;
            f[8]=fc2.x; f[9]=fc2.y;
            #pragma unroll
            for (int k = 0; k < 3; ++k) {
                const float* wrow = &Ws[c * 3 + k][o0];
                float4 wa = *(const float4*)&wrow[0];
                float4 wb = *(const float4*)&wrow[4];
                float w[8] = {wa.x, wa.y, wa.z, wa.w, wb.x, wb.y, wb.z, wb.w};
                #pragma unroll
                for (int oi = 0; oi < 8; ++oi)
                    #pragma unroll
                    for (int li = 0; li < 8; ++li)
                        acc[oi][li] = fmaf(w[oi], f[li + k], acc[oi][li]);
            }
        }
    }
    const int mflag = *mflag_p;
    const int lbase = l0 + ll;
    float mv[8];
    #pragma unroll
    for (int li = 0; li < 8; ++li) {
        int idx = b * L_ + lbase + li;
        if (mflag == 1)      mv[li] = mask[idx] ? 1.f : 0.f;
        else if (mflag == 0) mv[li] = ((const int*)mask)[idx] ? 1.f : 0.f;
        else                 mv[li] = ((const int*)mask)[2 * idx] ? 1.f : 0.f;
    }
    #pragma unroll
    for (int oi = 0; oi < 8; ++oi) {
        float bo = bias[o0 + oi];
        float* dst = out + ((size_t)b * O_ + o0 + oi) * L_ + lbase;
        #pragma unroll
        for (int li = 0; li < 8; ++li) dst[li] = (acc[oi][li] + bo) * mv[li];
    }
}

extern "C" void kernel_launch(void* const* d_in, const int* in_sizes, int n_in,
                              void* d_out, int out_size, void* d_ws, size_t ws_size,
                              hipStream_t stream) {
    const float*         inputs = (const float*)d_in[0];
    const int*           conn   = (const int*)d_in[1];
    const unsigned char* mask   = (const unsigned char*)d_in[2];
    const float*         W      = (const float*)d_in[3];
    const float*         bias   = (const float*)d_in[4];
    float*               out    = (float*)d_out;

    const size_t g_bytes  = G_ELEMS * sizeof(float);
    const size_t wt_bytes = WT_ELEMS * sizeof(float);
    const size_t need     = g_bytes + wt_bytes + 16;

    if (ws_size < need) {
        int* mflag = (int*)d_ws;
        detect_mask_kernel<<<1, 256, 0, stream>>>(mask, mflag);
        dim3 grid(L_ / 128, B_);
        cc_fallback_kernel<<<grid, 256, 0, stream>>>(inputs, conn, mask, W, bias, out, mflag);
        return;
    }

    float* G     = (float*)d_ws;
    float* Wt    = (float*)((char*)d_ws + g_bytes);
    int*   mflag = (int*)((char*)d_ws + g_bytes + wt_bytes);

    detect_mask_kernel<<<1, 256, 0, stream>>>(mask, mflag);
    k0_transpose<<<2048, 256, 0, stream>>>(inputs, G);
    k1b_wt<<<(int)((WT_ELEMS + 255) / 256), 256, 0, stream>>>(W, Wt);
    k1_gather_penc<<<1024, 256, 0, stream>>>(conn, G);
    dim3 grid2(L_ / TL2, B_);
    k2_gemm<<<grid2, 512, 0, stream>>>(G, Wt, mask, bias, out, mflag);
}

// Round 6
// 106.776 us; speedup vs baseline: 3.1938x; 1.6497x over previous
//
#include <hip/hip_runtime.h>
#include <math.h>

#define B_    8
#define C_    128
#define L_    8192
#define O_    128
#define POS_  10
#define CHIN  798
#define CH_   266          // 128 direct + 128 gathered + 10 penc
#define CPAD  288          // 9 chunks * 32
#define NCH   9            // K chunks of 32 channels
#define TL2   256          // l-tile for GEMM
#define G_ELEMS  ((size_t)B_ * L_ * CPAD)         // 18,874,368 f32
#define WT_ELEMS ((size_t)3 * O_ * CPAD)          // 110,592 f32

typedef short short8 __attribute__((ext_vector_type(8)));
typedef float f32x4  __attribute__((ext_vector_type(4)));

__device__ __forceinline__ unsigned bf16_rne(float f) {
    unsigned u = __float_as_uint(f);
    return (u + 0x7FFFu + ((u >> 16) & 1u)) >> 16;
}

// ---------------------------------------------------------------------------
// Parallel mask dtype detection. flags[0]=sub (nonzero byte at off%4!=0),
// flags[1]=mid (nonzero byte at off%8==4). mflag derived by consumers:
//   sub ? 1 (byte/bool) : (mid ? 0 (int32) : 2 (int64))
// ---------------------------------------------------------------------------
__global__ void init_flags_kernel(int* __restrict__ flags) {
    if (threadIdx.x < 2) flags[threadIdx.x] = 0;
}

// 16 blocks x 256 threads x 16B = 65536 bytes (= B_*L_ bytes; valid under
// every dtype interpretation, matches the R0 byte-loop semantics exactly).
__global__ void detect_mask_par(const uint4* __restrict__ m, int* __restrict__ flags) {
    int t = blockIdx.x * 256 + threadIdx.x;        // 0..4095
    uint4 w = m[t];
    // words j = 4t+0,1,2,3 ; byte off%4!=0  -> upper 3 bytes of any word
    // byte off%8==4 -> low byte of odd words (w.y, w.w)
    unsigned sub = (w.x | w.y | w.z | w.w) & 0xFFFFFF00u;
    unsigned mid = (w.y | w.w) & 0x000000FFu;
    unsigned long long bs = __ballot(sub != 0);
    unsigned long long bm = __ballot(mid != 0);
    if ((threadIdx.x & 63) == 0) {
        if (bs) atomicOr(&flags[0], 1);
        if (bm) atomicOr(&flags[1], 1);
    }
}

__device__ __forceinline__ int derive_mflag(const int* __restrict__ flags) {
    return flags[0] ? 1 : (flags[1] ? 0 : 2);
}

// ---------------------------------------------------------------------------
// K0: transpose inputs[b,c,l] -> G[b,l,c] (direct channels 0..127), f32
// ---------------------------------------------------------------------------
__global__ __launch_bounds__(256, 4)
void k0_transpose(const float* __restrict__ inputs, float* __restrict__ G) {
    __shared__ float tile[64][65];
    const int bid = blockIdx.x;
    const int b  = bid & 7;          // b -> XCD affinity
    const int r  = bid >> 3;
    const int c0 = (r & 1) * 64;
    const int l0 = (r >> 1) * 64;
    const int ty = threadIdx.x >> 6, tx = threadIdx.x & 63;

    #pragma unroll
    for (int it = 0; it < 16; ++it) {
        int cl = it * 4 + ty;
        tile[cl][tx] = inputs[((size_t)(b * C_ + c0 + cl)) * L_ + l0 + tx];
    }
    __syncthreads();
    #pragma unroll
    for (int it = 0; it < 16; ++it) {
        int ll = it * 4 + ty;
        G[((size_t)(b * L_ + l0 + ll)) * CPAD + c0 + tx] = tile[tx][ll];
    }
}

// ---------------------------------------------------------------------------
// K1: gather rows + positional encoding into G
//   G[b,l,128+c] = G[b,conn[b,l],c]  (c<128)
//   G[b,l,256+p] = sin(2^p * (l-conn)/1000) for p<10, else 0 (p<32)
// ---------------------------------------------------------------------------
__global__ __launch_bounds__(256, 4)
void k1_gather_penc(const int* __restrict__ conn, float* __restrict__ G) {
    const int bid = blockIdx.x;
    const int b  = bid & 7;                  // same-b blocks share an XCD's L2
    const int l0 = (bid >> 3) * 64;
    const int tid = threadIdx.x;
    const int wv = tid >> 6, lane = tid & 63;

    for (int i = 0; i < 16; ++i) {
        int l  = l0 + wv * 16 + i;
        int cj = conn[b * L_ + l];
        float2 s = *(const float2*)&G[((size_t)(b * L_ + cj)) * CPAD + lane * 2];
        *(float2*)&G[((size_t)(b * L_ + l)) * CPAD + 128 + lane * 2] = s;
    }

    // penc: 64 l x 32 c' per block; thread -> (l, 8-wide c' group)
    {
        int l   = l0 + (tid >> 2);
        int sub = tid & 3;
        int cj  = conn[b * L_ + l];
        float d = (float)(l - cj);
        float v[8];
        #pragma unroll
        for (int e = 0; e < 8; ++e) {
            int p = sub * 8 + e;
            if (p < POS_) {
                float sc = (float)(1 << p);
                v[e] = sinf((sc * d) / 1000.0f);
            } else v[e] = 0.f;
        }
        float* dst = &G[((size_t)(b * L_ + l)) * CPAD + 256 + sub * 8];
        *(float4*)&dst[0] = make_float4(v[0], v[1], v[2], v[3]);
        *(float4*)&dst[4] = make_float4(v[4], v[5], v[6], v[7]);
    }
}

// ---------------------------------------------------------------------------
// K1b: Wt[tap][o][c] = W[o][3c+tap] (c<266 else 0)
// ---------------------------------------------------------------------------
__global__ void k1b_wt(const float* __restrict__ W, float* __restrict__ Wt) {
    int idx = blockIdx.x * 256 + threadIdx.x;
    if (idx >= (int)WT_ELEMS) return;
    int c   = idx % CPAD;
    int rem = idx / CPAD;
    int o   = rem & 127;
    int t   = rem >> 7;
    Wt[idx] = (c < CH_) ? W[o * CHIN + 3 * c + t] : 0.f;
}

// ---------------------------------------------------------------------------
// K2: MFMA GEMM. block = (b, 256-l tile), 512 threads = 8 waves (2o x 4l).
// wave tile 64o x 64l = 16 frags of 16x16; K = 9 chunks x 32 ch x 3 taps,
// bf16x3 split (AhBh + AlBh + AhBl).
// ---------------------------------------------------------------------------
__global__ __launch_bounds__(512, 2)
void k2_gemm(const float* __restrict__ G, const float* __restrict__ Wt,
             const unsigned char* __restrict__ mask,
             const float* __restrict__ bias,
             float* __restrict__ out,
             const int* __restrict__ flags_p) {
    __shared__ short Bs_h[260][40];    // rows l0-1 .. l0+256 ; stride 40 bf16 = 80B
    __shared__ short Bs_l[260][40];
    __shared__ short As_h[3][128][40]; // [tap][o][c]
    __shared__ short As_l[3][128][40];

    const int lt0 = blockIdx.x;        // 0..31
    const int b   = blockIdx.y;
    const int l0  = lt0 * TL2;
    const int tid  = threadIdx.x;
    const int wave = tid >> 6;
    const int lane = tid & 63;
    const int wo = wave & 1;           // o-half
    const int wl = wave >> 1;          // l-quarter
    const int g  = lane >> 4;          // k-group 0..3
    const int ln = lane & 15;

    f32x4 acc[4][4];
    #pragma unroll
    for (int m = 0; m < 4; ++m)
        #pragma unroll
        for (int n = 0; n < 4; ++n) acc[m][n] = (f32x4)0.f;

    for (int ch = 0; ch < NCH; ++ch) {
        const int c0 = ch * 32;
        __syncthreads();

        // stage A: Wt[t][o][c0..c0+31] -> bf16 hi/lo ; 3072 float4-quads
        for (int q = tid; q < 3072; q += 512) {
            int c4 = (q & 7) * 4;
            int o  = (q >> 3) & 127;
            int t  = q >> 10;
            float4 w4 = *(const float4*)&Wt[((size_t)(t * O_ + o)) * CPAD + c0 + c4];
            unsigned h0 = bf16_rne(w4.x), h1 = bf16_rne(w4.y), h2 = bf16_rne(w4.z), h3 = bf16_rne(w4.w);
            float l0f = w4.x - __uint_as_float(h0 << 16);
            float l1f = w4.y - __uint_as_float(h1 << 16);
            float l2f = w4.z - __uint_as_float(h2 << 16);
            float l3f = w4.w - __uint_as_float(h3 << 16);
            uint2 hw, lw;
            hw.x = h0 | (h1 << 16); hw.y = h2 | (h3 << 16);
            lw.x = bf16_rne(l0f) | (bf16_rne(l1f) << 16);
            lw.y = bf16_rne(l2f) | (bf16_rne(l3f) << 16);
            *(uint2*)&As_h[t][o][c4] = hw;
            *(uint2*)&As_l[t][o][c4] = lw;
        }

        // stage B: G[b][l0-1+j][c0..c0+31] -> bf16 hi/lo ; 258 rows x 8 quads
        for (int q = tid; q < 2064; q += 512) {
            int c4 = (q & 7) * 4;
            int j  = q >> 3;
            int l  = l0 - 1 + j;
            float4 g4 = make_float4(0.f, 0.f, 0.f, 0.f);
            if ((unsigned)l < (unsigned)L_)
                g4 = *(const float4*)&G[((size_t)(b * L_ + l)) * CPAD + c0 + c4];
            unsigned h0 = bf16_rne(g4.x), h1 = bf16_rne(g4.y), h2 = bf16_rne(g4.z), h3 = bf16_rne(g4.w);
            float l0f = g4.x - __uint_as_float(h0 << 16);
            float l1f = g4.y - __uint_as_float(h1 << 16);
            float l2f = g4.z - __uint_as_float(h2 << 16);
            float l3f = g4.w - __uint_as_float(h3 << 16);
            uint2 hw, lw;
            hw.x = h0 | (h1 << 16); hw.y = h2 | (h3 << 16);
            lw.x = bf16_rne(l0f) | (bf16_rne(l1f) << 16);
            lw.y = bf16_rne(l2f) | (bf16_rne(l3f) << 16);
            *(uint2*)&Bs_h[j][c4] = hw;
            *(uint2*)&Bs_l[j][c4] = lw;
        }

        __syncthreads();

        // compute: 3 taps x (4m x 4n) x 3 split terms
        #pragma unroll
        for (int t = 0; t < 3; ++t) {
            short8 bh[4], bl[4];
            #pragma unroll
            for (int n = 0; n < 4; ++n) {
                int row = wl * 64 + n * 16 + ln + t;   // = (l - l0) + (t-1) + 1
                bh[n] = *(const short8*)&Bs_h[row][8 * g];
                bl[n] = *(const short8*)&Bs_l[row][8 * g];
            }
            #pragma unroll
            for (int m = 0; m < 4; ++m) {
                int orow = wo * 64 + m * 16 + ln;
                short8 ah = *(const short8*)&As_h[t][orow][8 * g];
                short8 al = *(const short8*)&As_l[t][orow][8 * g];
                #pragma unroll
                for (int n = 0; n < 4; ++n) {
                    acc[m][n] = __builtin_amdgcn_mfma_f32_16x16x32_bf16(ah, bh[n], acc[m][n], 0, 0, 0);
                    acc[m][n] = __builtin_amdgcn_mfma_f32_16x16x32_bf16(al, bh[n], acc[m][n], 0, 0, 0);
                    acc[m][n] = __builtin_amdgcn_mfma_f32_16x16x32_bf16(ah, bl[n], acc[m][n], 0, 0, 0);
                }
            }
        }
    }

    // epilogue: bias + mask + store. D: col = lane&15 (l), row = (lane>>4)*4+r (o)
    const int mflag = derive_mflag(flags_p);
    float mv[4];
    #pragma unroll
    for (int n = 0; n < 4; ++n) {
        int l = l0 + wl * 64 + n * 16 + ln;
        int idx = b * L_ + l;
        if (mflag == 1)      mv[n] = mask[idx] ? 1.f : 0.f;
        else if (mflag == 0) mv[n] = ((const int*)mask)[idx] ? 1.f : 0.f;
        else                 mv[n] = ((const int*)mask)[2 * idx] ? 1.f : 0.f;
    }
    #pragma unroll
    for (int m = 0; m < 4; ++m) {
        #pragma unroll
        for (int r = 0; r < 4; ++r) {
            int o = wo * 64 + m * 16 + g * 4 + r;
            float bo = bias[o];
            #pragma unroll
            for (int n = 0; n < 4; ++n) {
                int l = l0 + wl * 64 + n * 16 + ln;
                out[((size_t)(b * O_ + o)) * L_ + l] = (acc[m][n][r] + bo) * mv[n];
            }
        }
    }
}

// ---------------------------------------------------------------------------
// Fallback (R1 fp32 kernel) if workspace is too small for the MFMA path
// ---------------------------------------------------------------------------
__global__ __launch_bounds__(256, 2)
void cc_fallback_kernel(const float* __restrict__ inputs,
                        const int* __restrict__ conn,
                        const unsigned char* __restrict__ mask,
                        const float* __restrict__ W,
                        const float* __restrict__ bias,
                        float* __restrict__ out,
                        const int* __restrict__ flags_p) {
    __shared__ int   conn_s[130];
    __shared__ float feat_s[16][132];
    __shared__ float Ws[48][136];

    const int b   = blockIdx.y;
    const int l0  = blockIdx.x * 128;
    const int tid = threadIdx.x;
    const int ot  = tid >> 4;
    const int lt  = tid & 15;
    const int o0  = ot * 8;
    const int ll  = lt * 8;

    for (int j = tid; j < 130; j += 256) {
        int lg = l0 - 1 + j;
        conn_s[j] = ((unsigned)lg < (unsigned)L_) ? conn[b * L_ + lg] : -1;
    }
    float acc[8][8];
    #pragma unroll
    for (int i = 0; i < 8; ++i)
        #pragma unroll
        for (int j = 0; j < 8; ++j) acc[i][j] = 0.f;

    const int tc = ot, tj = lt;
    for (int chunk = 0; chunk < 17; ++chunk) {
        const int CN  = (chunk < 16) ? 16 : POS_;
        const int cg0 = chunk * 16;
        const int col0 = 3 * cg0;
        __syncthreads();
        {
            const int nw = O_ * CN * 3;
            for (int idx = tid; idx < nw; idx += 256) {
                int o = idx & 127, kk = idx >> 7;
                Ws[kk][o] = W[o * CHIN + col0 + kk];
            }
        }
        if (chunk < 8) {
            const float* src = inputs + ((size_t)b * C_ + (cg0 + tc)) * L_;
            for (int j = tj; j < 130; j += 16) {
                int lg = l0 - 1 + j;
                feat_s[tc][j] = ((unsigned)lg < (unsigned)L_) ? src[lg] : 0.f;
            }
        } else if (chunk < 16) {
            const float* src = inputs + ((size_t)b * C_ + (cg0 - 128 + tc)) * L_;
            for (int j = tj; j < 130; j += 16) {
                int cj = conn_s[j];
                feat_s[tc][j] = (cj >= 0) ? src[cj] : 0.f;
            }
        } else if (tc < POS_) {
            const float sc = (float)(1 << tc);
            for (int j = tj; j < 130; j += 16) {
                int cj = conn_s[j];
                int lg = l0 - 1 + j;
                float v = 0.f;
                if (cj >= 0) v = sinf((sc * (float)(lg - cj)) / 1000.0f);
                feat_s[tc][j] = v;
            }
        }
        __syncthreads();
        for (int c = 0; c < CN; ++c) {
            float f[10];
            float4 fa = *(const float4*)&feat_s[c][ll];
            float4 fb = *(const float4*)&feat_s[c][ll + 4];
            float2 fc2 = *(const float2*)&feat_s[c][ll + 8];
            f[0]=fa.x; f[1]=fa.y; f[2]=fa.z; f[3]=fa.w;
            f[4]=fb.x; f[5]=fb.y; f[6]=fb.z; f[7]=fb.w;
            f[8]=fc2.x; f[9]=fc2.y;
            #pragma unroll
            for (int k = 0; k < 3; ++k) {
                const float* wrow = &Ws[c * 3 + k][o0];
                float4 wa = *(const float4*)&wrow[0];
                float4 wb = *(const float4*)&wrow[4];
                float w[8] = {wa.x, wa.y, wa.z, wa.w, wb.x, wb.y, wb.z, wb.w};
                #pragma unroll
                for (int oi = 0; oi < 8; ++oi)
                    #pragma unroll
                    for (int li = 0; li < 8; ++li)
                        acc[oi][li] = fmaf(w[oi], f[li + k], acc[oi][li]);
            }
        }
    }
    const int mflag = derive_mflag(flags_p);
    const int lbase = l0 + ll;
    float mv[8];
    #pragma unroll
    for (int li = 0; li < 8; ++li) {
        int idx = b * L_ + lbase + li;
        if (mflag == 1)      mv[li] = mask[idx] ? 1.f : 0.f;
        else if (mflag == 0) mv[li] = ((const int*)mask)[idx] ? 1.f : 0.f;
        else                 mv[li] = ((const int*)mask)[2 * idx] ? 1.f : 0.f;
    }
    #pragma unroll
    for (int oi = 0; oi < 8; ++oi) {
        float bo = bias[o0 + oi];
        float* dst = out + ((size_t)b * O_ + o0 + oi) * L_ + lbase;
        #pragma unroll
        for (int li = 0; li < 8; ++li) dst[li] = (acc[oi][li] + bo) * mv[li];
    }
}

extern "C" void kernel_launch(void* const* d_in, const int* in_sizes, int n_in,
                              void* d_out, int out_size, void* d_ws, size_t ws_size,
                              hipStream_t stream) {
    const float*         inputs = (const float*)d_in[0];
    const int*           conn   = (const int*)d_in[1];
    const unsigned char* mask   = (const unsigned char*)d_in[2];
    const float*         W      = (const float*)d_in[3];
    const float*         bias   = (const float*)d_in[4];
    float*               out    = (float*)d_out;

    const size_t g_bytes  = G_ELEMS * sizeof(float);
    const size_t wt_bytes = WT_ELEMS * sizeof(float);
    const size_t need     = g_bytes + wt_bytes + 64;

    if (ws_size < need) {
        int* flags = (int*)d_ws;
        init_flags_kernel<<<1, 64, 0, stream>>>(flags);
        detect_mask_par<<<16, 256, 0, stream>>>((const uint4*)mask, flags);
        dim3 grid(L_ / 128, B_);
        cc_fallback_kernel<<<grid, 256, 0, stream>>>(inputs, conn, mask, W, bias, out, flags);
        return;
    }

    float* G     = (float*)d_ws;
    float* Wt    = (float*)((char*)d_ws + g_bytes);
    int*   flags = (int*)((char*)d_ws + g_bytes + wt_bytes);

    init_flags_kernel<<<1, 64, 0, stream>>>(flags);
    detect_mask_par<<<16, 256, 0, stream>>>((const uint4*)mask, flags);
    k0_transpose<<<2048, 256, 0, stream>>>(inputs, G);
    k1b_wt<<<(int)((WT_ELEMS + 255) / 256), 256, 0, stream>>>(W, Wt);
    k1_gather_penc<<<1024, 256, 0, stream>>>(conn, G);
    dim3 grid2(L_ / TL2, B_);
    k2_gemm<<<grid2, 512, 0, stream>>>(G, Wt, mask, bias, out, flags);
}

// Round 7
// 66.876 us; speedup vs baseline: 5.0994x; 1.5966x over previous
//
#include <hip/hip_runtime.h>
#include <math.h>

#define B_    8
#define C_    128
#define L_    8192
#define O_    128
#define POS_  10
#define CHIN  798
#define CH_   266          // 128 direct + 128 gathered + 10 penc
#define CPAD  288          // 9 chunks * 32
#define NCH   9
#define TL2   256
#define G_ELEMS  ((size_t)B_ * L_ * CPAD)   // f16 elems: 18.87M -> 37.75 MB
#define WT_ELEMS ((size_t)3 * O_ * CPAD)    // f16 elems: 110,592 -> 221 KB

typedef _Float16 half8 __attribute__((ext_vector_type(8)));
typedef short short8 __attribute__((ext_vector_type(8)));
typedef float f32x4  __attribute__((ext_vector_type(4)));

// ---------------------------------------------------------------------------
// Parallel mask dtype detection. flags[0]=sub, flags[1]=mid.
// mflag = sub ? 1 (byte) : (mid ? 0 (int32) : 2 (int64))
// ---------------------------------------------------------------------------
__global__ void init_flags_kernel(int* __restrict__ flags) {
    if (threadIdx.x < 2) flags[threadIdx.x] = 0;
}

__global__ void detect_mask_par(const uint4* __restrict__ m, int* __restrict__ flags) {
    int t = blockIdx.x * 256 + threadIdx.x;        // 0..4095 ; 4096*16B = 64KB
    uint4 w = m[t];
    unsigned sub = (w.x | w.y | w.z | w.w) & 0xFFFFFF00u;
    unsigned mid = (w.y | w.w) & 0x000000FFu;
    unsigned long long bs = __ballot(sub != 0);
    unsigned long long bm = __ballot(mid != 0);
    if ((threadIdx.x & 63) == 0) {
        if (bs) atomicOr(&flags[0], 1);
        if (bm) atomicOr(&flags[1], 1);
    }
}

__device__ __forceinline__ int derive_mflag(const int* __restrict__ flags) {
    return flags[0] ? 1 : (flags[1] ? 0 : 2);
}

// ---------------------------------------------------------------------------
// K0: transpose inputs[b,c,l] f32 -> G[b,l,c] f16 (channels 0..127)
// ---------------------------------------------------------------------------
__global__ __launch_bounds__(256, 4)
void k0_transpose(const float* __restrict__ inputs, _Float16* __restrict__ G) {
    __shared__ float tile[64][65];
    const int bid = blockIdx.x;
    const int b  = bid & 7;
    const int r  = bid >> 3;
    const int c0 = (r & 1) * 64;
    const int l0 = (r >> 1) * 64;
    const int tid = threadIdx.x;
    const int ty = tid >> 6, tx = tid & 63;

    #pragma unroll
    for (int it = 0; it < 16; ++it) {
        int cl = it * 4 + ty;
        tile[cl][tx] = inputs[((size_t)(b * C_ + c0 + cl)) * L_ + l0 + tx];
    }
    __syncthreads();
    // writer: lane -> (c pair, l row); 32 lanes * 4B = 128B contiguous runs
    const int cp = (tid & 31) * 2;
    const int lr = tid >> 5;          // 0..7
    #pragma unroll
    for (int it = 0; it < 8; ++it) {
        int ll = it * 8 + lr;
        _Float16 h0 = (_Float16)tile[cp][ll];
        _Float16 h1 = (_Float16)tile[cp + 1][ll];
        _Float16 pair[2] = {h0, h1};
        *(unsigned*)&G[((size_t)(b * L_ + l0 + ll)) * CPAD + c0 + cp] = *(unsigned*)pair;
    }
}

// ---------------------------------------------------------------------------
// K1: gather rows + positional encoding into G (f16)
//   G[b,l,128+c] = G[b,conn[b,l],c]  (c<128)
//   G[b,l,256+p] = sin(2^p*(l-conn)/1000) for p<10, else 0
// ---------------------------------------------------------------------------
__global__ __launch_bounds__(256, 4)
void k1_gather_penc(const int* __restrict__ conn, _Float16* __restrict__ G) {
    const int bid = blockIdx.x;
    const int b  = bid & 7;
    const int l0 = (bid >> 3) * 64;
    const int tid = threadIdx.x;
    const int wv = tid >> 6, lane = tid & 63;

    for (int i = 0; i < 16; ++i) {
        int l  = l0 + wv * 16 + i;
        int cj = conn[b * L_ + l];
        unsigned v = *(const unsigned*)&G[((size_t)(b * L_ + cj)) * CPAD + lane * 2];
        *(unsigned*)&G[((size_t)(b * L_ + l)) * CPAD + 128 + lane * 2] = v;
    }

    {
        int l = l0 + (tid >> 2);
        int s = tid & 3;
        int cj = conn[b * L_ + l];
        float d = (float)(l - cj);
        _Float16 v[8];
        #pragma unroll
        for (int e = 0; e < 8; ++e) {
            int p = s * 8 + e;
            if (p < POS_) {
                float sc = (float)(1 << p);
                v[e] = (_Float16)sinf((sc * d) / 1000.0f);
            } else v[e] = (_Float16)0.f;
        }
        *(short8*)&G[((size_t)(b * L_ + l)) * CPAD + 256 + s * 8] = *(short8*)v;
    }
}

// ---------------------------------------------------------------------------
// K1b: Wt[t][o][c] = (f16) W[o][3c+t]  (c<266 else 0)
// ---------------------------------------------------------------------------
__global__ void k1b_wt(const float* __restrict__ W, _Float16* __restrict__ Wt) {
    int idx = blockIdx.x * 256 + threadIdx.x;
    if (idx >= (int)WT_ELEMS) return;
    int c   = idx % CPAD;
    int rem = idx / CPAD;
    int o   = rem & 127;
    int t   = rem >> 7;
    Wt[idx] = (c < CH_) ? (_Float16)W[o * CHIN + 3 * c + t] : (_Float16)0.f;
}

// ---------------------------------------------------------------------------
// K2: f16 MFMA GEMM. block = (b, 256-l tile), 512 thr = 8 waves (2o x 4l).
// wave = 64o x 64l (m=4, n=4). 9 chunks of 32 ch; 3 taps; SINGLE f16 term.
// ---------------------------------------------------------------------------
__global__ __launch_bounds__(512, 4)
void k2_gemm(const _Float16* __restrict__ G, const _Float16* __restrict__ Wt,
             const unsigned char* __restrict__ mask,
             const float* __restrict__ bias,
             float* __restrict__ out,
             const int* __restrict__ flags_p) {
    __shared__ _Float16 As[3][128][40];   // [tap][o][c] stride 40 f16 = 80B
    __shared__ _Float16 Bs[260][40];      // rows l0-1 .. l0+256

    const int lt0 = blockIdx.x;
    const int b   = blockIdx.y;
    const int l0  = lt0 * TL2;
    const int tid  = threadIdx.x;
    const int wave = tid >> 6;
    const int lane = tid & 63;
    const int wo = wave & 1;
    const int wl = wave >> 1;
    const int g  = lane >> 4;
    const int ln = lane & 15;

    f32x4 acc[4][4];
    #pragma unroll
    for (int m = 0; m < 4; ++m)
        #pragma unroll
        for (int n = 0; n < 4; ++n) acc[m][n] = (f32x4)0.f;

    for (int ch = 0; ch < NCH; ++ch) {
        const int c0 = ch * 32;
        __syncthreads();

        // stage A: 3*128*4 = 1536 16B blocks, pure copy
        for (int q = tid; q < 1536; q += 512) {
            int cb = q & 3;
            int o  = (q >> 2) & 127;
            int t  = q >> 9;
            *(short8*)&As[t][o][cb * 8] =
                *(const short8*)&Wt[((size_t)(t * O_ + o)) * CPAD + c0 + cb * 8];
        }
        // stage B: 258 rows * 4 blocks = 1032, pure copy + halo zero
        for (int q = tid; q < 1032; q += 512) {
            int cb = q & 3;
            int j  = q >> 2;
            int l  = l0 - 1 + j;
            short8 v = (short8)0;
            if ((unsigned)l < (unsigned)L_)
                v = *(const short8*)&G[((size_t)(b * L_ + l)) * CPAD + c0 + cb * 8];
            *(short8*)&Bs[j][cb * 8] = v;
        }

        __syncthreads();

        #pragma unroll
        for (int t = 0; t < 3; ++t) {
            half8 bf[4];
            #pragma unroll
            for (int n = 0; n < 4; ++n)
                bf[n] = *(const half8*)&Bs[wl * 64 + n * 16 + ln + t][8 * g];
            #pragma unroll
            for (int m = 0; m < 4; ++m) {
                half8 af = *(const half8*)&As[t][wo * 64 + m * 16 + ln][8 * g];
                #pragma unroll
                for (int n = 0; n < 4; ++n)
                    acc[m][n] = __builtin_amdgcn_mfma_f32_16x16x32_f16(af, bf[n], acc[m][n], 0, 0, 0);
            }
        }
    }

    // epilogue: D col = lane&15 (l), row = g*4+r (o) within frag
    const int mflag = derive_mflag(flags_p);
    float mv[4];
    #pragma unroll
    for (int n = 0; n < 4; ++n) {
        int l = l0 + wl * 64 + n * 16 + ln;
        int idx = b * L_ + l;
        if (mflag == 1)      mv[n] = mask[idx] ? 1.f : 0.f;
        else if (mflag == 0) mv[n] = ((const int*)mask)[idx] ? 1.f : 0.f;
        else                 mv[n] = ((const int*)mask)[2 * idx] ? 1.f : 0.f;
    }
    #pragma unroll
    for (int m = 0; m < 4; ++m) {
        #pragma unroll
        for (int r = 0; r < 4; ++r) {
            int o = wo * 64 + m * 16 + g * 4 + r;
            float bo = bias[o];
            #pragma unroll
            for (int n = 0; n < 4; ++n) {
                int l = l0 + wl * 64 + n * 16 + ln;
                out[((size_t)(b * O_ + o)) * L_ + l] = (acc[m][n][r] + bo) * mv[n];
            }
        }
    }
}

// ---------------------------------------------------------------------------
// Fallback (fp32 vector path) if workspace too small
// ---------------------------------------------------------------------------
__global__ __launch_bounds__(256, 2)
void cc_fallback_kernel(const float* __restrict__ inputs,
                        const int* __restrict__ conn,
                        const unsigned char* __restrict__ mask,
                        const float* __restrict__ W,
                        const float* __restrict__ bias,
                        float* __restrict__ out,
                        const int* __restrict__ flags_p) {
    __shared__ int   conn_s[130];
    __shared__ float feat_s[16][132];
    __shared__ float Ws[48][136];

    const int b   = blockIdx.y;
    const int l0  = blockIdx.x * 128;
    const int tid = threadIdx.x;
    const int ot  = tid >> 4;
    const int lt  = tid & 15;
    const int o0  = ot * 8;
    const int ll  = lt * 8;

    for (int j = tid; j < 130; j += 256) {
        int lg = l0 - 1 + j;
        conn_s[j] = ((unsigned)lg < (unsigned)L_) ? conn[b * L_ + lg] : -1;
    }
    float acc[8][8];
    #pragma unroll
    for (int i = 0; i < 8; ++i)
        #pragma unroll
        for (int j = 0; j < 8; ++j) acc[i][j] = 0.f;

    const int tc = ot, tj = lt;
    for (int chunk = 0; chunk < 17; ++chunk) {
        const int CN  = (chunk < 16) ? 16 : POS_;
        const int cg0 = chunk * 16;
        const int col0 = 3 * cg0;
        __syncthreads();
        {
            const int nw = O_ * CN * 3;
            for (int idx = tid; idx < nw; idx += 256) {
                int o = idx & 127, kk = idx >> 7;
                Ws[kk][o] = W[o * CHIN + col0 + kk];
            }
        }
        if (chunk < 8) {
            const float* src = inputs + ((size_t)b * C_ + (cg0 + tc)) * L_;
            for (int j = tj; j < 130; j += 16) {
                int lg = l0 - 1 + j;
                feat_s[tc][j] = ((unsigned)lg < (unsigned)L_) ? src[lg] : 0.f;
            }
        } else if (chunk < 16) {
            const float* src = inputs + ((size_t)b * C_ + (cg0 - 128 + tc)) * L_;
            for (int j = tj; j < 130; j += 16) {
                int cj = conn_s[j];
                feat_s[tc][j] = (cj >= 0) ? src[cj] : 0.f;
            }
        } else if (tc < POS_) {
            const float sc = (float)(1 << tc);
            for (int j = tj; j < 130; j += 16) {
                int cj = conn_s[j];
                int lg = l0 - 1 + j;
                float v = 0.f;
                if (cj >= 0) v = sinf((sc * (float)(lg - cj)) / 1000.0f);
                feat_s[tc][j] = v;
            }
        }
        __syncthreads();
        for (int c = 0; c < CN; ++c) {
            float f[10];
            float4 fa = *(const float4*)&feat_s[c][ll];
            float4 fb = *(const float4*)&feat_s[c][ll + 4];
            float2 fc2 = *(const float2*)&feat_s[c][ll + 8];
            f[0]=fa.x; f[1]=fa.y; f[2]=fa.z; f[3]=fa.w;
            f[4]=fb.x; f[5]=fb.y; f[6]=fb.z; f[7]=fb.w;
            f[8]=fc2.x; f[9]=fc2.y;
            #pragma unroll
            for (int k = 0; k < 3; ++k) {
                const float* wrow = &Ws[c * 3 + k][o0];
                float4 wa = *(const float4*)&wrow[0];
                float4 wb = *(const float4*)&wrow[4];
                float w[8] = {wa.x, wa.y, wa.z, wa.w, wb.x, wb.y, wb.z, wb.w};
                #pragma unroll
                for (int oi = 0; oi < 8; ++oi)
                    #pragma unroll
                    for (int li = 0; li < 8; ++li)
                        acc[oi][li] = fmaf(w[oi], f[li + k], acc[oi][li]);
            }
        }
    }
    const int mflag = derive_mflag(flags_p);
    const int lbase = l0 + ll;
    float mv[8];
    #pragma unroll
    for (int li = 0; li < 8; ++li) {
        int idx = b * L_ + lbase + li;
        if (mflag == 1)      mv[li] = mask[idx] ? 1.f : 0.f;
        else if (mflag == 0) mv[li] = ((const int*)mask)[idx] ? 1.f : 0.f;
        else                 mv[li] = ((const int*)mask)[2 * idx] ? 1.f : 0.f;
    }
    #pragma unroll
    for (int oi = 0; oi < 8; ++oi) {
        float bo = bias[o0 + oi];
        float* dst = out + ((size_t)b * O_ + o0 + oi) * L_ + lbase;
        #pragma unroll
        for (int li = 0; li < 8; ++li) dst[li] = (acc[oi][li] + bo) * mv[li];
    }
}

extern "C" void kernel_launch(void* const* d_in, const int* in_sizes, int n_in,
                              void* d_out, int out_size, void* d_ws, size_t ws_size,
                              hipStream_t stream) {
    const float*         inputs = (const float*)d_in[0];
    const int*           conn   = (const int*)d_in[1];
    const unsigned char* mask   = (const unsigned char*)d_in[2];
    const float*         W      = (const float*)d_in[3];
    const float*         bias   = (const float*)d_in[4];
    float*               out    = (float*)d_out;

    const size_t g_bytes  = G_ELEMS * sizeof(_Float16);    // 37.75 MB
    const size_t wt_bytes = WT_ELEMS * sizeof(_Float16);   // 221 KB
    const size_t need     = g_bytes + wt_bytes + 64;

    if (ws_size < need) {
        int* flags = (int*)d_ws;
        init_flags_kernel<<<1, 64, 0, stream>>>(flags);
        detect_mask_par<<<16, 256, 0, stream>>>((const uint4*)mask, flags);
        dim3 grid(L_ / 128, B_);
        cc_fallback_kernel<<<grid, 256, 0, stream>>>(inputs, conn, mask, W, bias, out, flags);
        return;
    }

    _Float16* G     = (_Float16*)d_ws;
    _Float16* Wt    = (_Float16*)((char*)d_ws + g_bytes);
    int*      flags = (int*)((char*)d_ws + g_bytes + wt_bytes);

    init_flags_kernel<<<1, 64, 0, stream>>>(flags);
    detect_mask_par<<<16, 256, 0, stream>>>((const uint4*)mask, flags);
    k0_transpose<<<2048, 256, 0, stream>>>(inputs, G);
    k1b_wt<<<(int)((WT_ELEMS + 255) / 256), 256, 0, stream>>>(W, Wt);
    k1_gather_penc<<<1024, 256, 0, stream>>>(conn, G);
    dim3 grid2(L_ / TL2, B_);
    k2_gemm<<<grid2, 512, 0, stream>>>(G, Wt, mask, bias, out, flags);
}